// Round 15
// baseline (60.506 us; speedup 1.0000x reference)
//
#include <hip/hip_runtime.h>

// SelfAttention2d, B=8 C=256 H=W=64 (N=4096), Ck=32, softmax dead code.
// out = gamma * (v q^T k) + x, reassociated:
//   Qt = X^T Wq^T + 1 bq^T      (N x 32, per-tile, LDS only)
//   Kt_t = X^T Wk^T             (N x 32, bf16, ws; bk folded into h)
//   T  = X Qt                   (256 x 32) n-chunked partials -> ws
//   qsum = Qt^T 1               (32)
//   P  = Wv T + bv qsum^T       (256 x 32), h = P bk  (j-split over 2 blocks)
//   out = gamma * (P Kt + h 1^T) + x
// R15 (single variable vs R14): k_wprep pre-converts Wq/Wk to bf16 in ws;
// front drops ldsW (B-frags = direct bf16x8 global loads, zero cvts, L1-hot)
// -> LDS 43 KB -> 3 blocks/CU (12 waves/CU, was 8). reduce/pgemm/back = R14.

constexpr int NB = 8;
constexpr int NC = 256;
constexpr int NK = 32;     // C/8
constexpr int NN = 4096;   // H*W
constexpr int NCHUNK = 64; // front n-chunks (64 n each)

typedef float  f32x4  __attribute__((ext_vector_type(4)));
typedef __bf16 bf16x4 __attribute__((ext_vector_type(4)));
typedef __bf16 bf16x8 __attribute__((ext_vector_type(8)));

__device__ __forceinline__ bf16x8 load_bf8(const float* __restrict__ p) {
  f32x4 a = *(const f32x4*)p;
  f32x4 b = *(const f32x4*)(p + 4);
  bf16x8 r;
  r[0] = (__bf16)a[0]; r[1] = (__bf16)a[1]; r[2] = (__bf16)a[2]; r[3] = (__bf16)a[3];
  r[4] = (__bf16)b[0]; r[5] = (__bf16)b[1]; r[6] = (__bf16)b[2]; r[7] = (__bf16)b[3];
  return r;
}

// ---------------- wprep: Wq/Wk f32[32][256] -> bf16 in ws ---------------------
// grid = 16 blocks (m = Wq/Wk, 8 j-slices), 256 threads, one 4-elem cvt each.
__global__ __launch_bounds__(256) void k_wprep(
    const float* __restrict__ Wq, const float* __restrict__ Wk,
    __bf16* __restrict__ Wqb, __bf16* __restrict__ Wkb) {
  int bid = blockIdx.x;
  int m = bid & 1, js = bid >> 1;
  const float* src = (m ? Wk : Wq) + js * 4 * NC;
  __bf16* dst = (m ? Wkb : Wqb) + js * 4 * NC;
  int t = threadIdx.x;
  f32x4 v = *(const f32x4*)(src + t * 4);
  bf16x4 pk = {(__bf16)v[0], (__bf16)v[1], (__bf16)v[2], (__bf16)v[3]};
  *(bf16x4*)(dst + t * 4) = pk;
}

// ---------------- front: Qt/Kt for one 64-n subtile; T partial; qsum partial --
// grid = NB*64 (512 blocks, 3/CU at 43 KB LDS), 256 threads (4 waves).
__global__ __launch_bounds__(256) void k_front(
    const float* __restrict__ x, const __bf16* __restrict__ Wqb,
    const float* __restrict__ bq, const __bf16* __restrict__ Wkb,
    __bf16* __restrict__ Tpart, __bf16* __restrict__ Kt_t,
    float* __restrict__ qsum_part) {
  __shared__ __bf16 ldsT[64 * 264];   // x-subtile transposed [n][c], XOR-swizzled
  __shared__ __bf16 ldsQt[32][72];    // Q^T subtile [j][n]
  __shared__ __bf16 ldsKtN[64][40];   // K^T subtile [n][j] (80B rows)
  __shared__ float  ldsQs[4][32];
  int bid = blockIdx.x;
  int b = bid >> 6, chunk = bid & 63;
  int nsub = chunk * 64;
  int t = threadIdx.x;
  int lane = t & 63, w = t >> 6, lr = lane & 15, lg = lane >> 4;
  const float* xb = x + (size_t)b * NC * NN;
  float bq0 = bq[lr], bq1 = bq[16 + lr];

  {  // stage x[0:256][nsub:nsub+64] -> ldsT swizzled, fully coalesced reads
    int cg = t >> 4, ng = t & 15;
    int n0 = ng * 4;
    int swzEl = (ng & 7) << 3;
#pragma unroll
    for (int r = 0; r < 4; ++r) {
      int c0 = r * 64 + cg * 4;
      const float* src = xb + (size_t)c0 * NN + nsub + n0;
      f32x4 L0 = *(const f32x4*)(src);
      f32x4 L1 = *(const f32x4*)(src + NN);
      f32x4 L2 = *(const f32x4*)(src + 2 * NN);
      f32x4 L3 = *(const f32x4*)(src + 3 * NN);
#pragma unroll
      for (int jj = 0; jj < 4; ++jj) {
        bf16x4 pk = {(__bf16)L0[jj], (__bf16)L1[jj], (__bf16)L2[jj], (__bf16)L3[jj]};
        *(bf16x4*)&ldsT[(n0 + jj) * 264 + (c0 ^ swzEl)] = pk;
      }
    }
  }
  __syncthreads();
  // Qt(64x32) and Kt(64x32): A from swizzled ldsT, B = bf16 W rows from global
  // (8 KB working set, L1-hot, zero cvts)
  f32x4 aq[2] = {}, ak[2] = {};
  {
    int n = w * 16 + lr;
    int swzA = ((n >> 2) & 7) << 3;
    int rowA = n * 264;
    const __bf16* wq0 = Wqb + (size_t)lr * NC;
    const __bf16* wq1 = Wqb + (size_t)(16 + lr) * NC;
    const __bf16* wk0 = Wkb + (size_t)lr * NC;
    const __bf16* wk1 = Wkb + (size_t)(16 + lr) * NC;
#pragma unroll
    for (int ks = 0; ks < 8; ++ks) {
      int off = ks * 32 + lg * 8;
      bf16x8 af = *(const bf16x8*)&ldsT[rowA + (off ^ swzA)];
      bf16x8 q0 = *(const bf16x8*)&wq0[off];
      bf16x8 q1 = *(const bf16x8*)&wq1[off];
      bf16x8 k0 = *(const bf16x8*)&wk0[off];
      bf16x8 k1 = *(const bf16x8*)&wk1[off];
      aq[0] = __builtin_amdgcn_mfma_f32_16x16x32_bf16(af, q0, aq[0], 0, 0, 0);
      aq[1] = __builtin_amdgcn_mfma_f32_16x16x32_bf16(af, q1, aq[1], 0, 0, 0);
      ak[0] = __builtin_amdgcn_mfma_f32_16x16x32_bf16(af, k0, ak[0], 0, 0, 0);
      ak[1] = __builtin_amdgcn_mfma_f32_16x16x32_bf16(af, k1, ak[1], 0, 0, 0);
    }
  }
  float qs0, qs1;
#pragma unroll
  for (int r = 0; r < 4; ++r) { aq[0][r] += bq0; aq[1][r] += bq1; }
  qs0 = aq[0][0] + aq[0][1] + aq[0][2] + aq[0][3];
  qs1 = aq[1][0] + aq[1][1] + aq[1][2] + aq[1][3];
  {  // Qt -> LDS [j][n]; Kt -> LDS [n][j]
    bf16x4 p0 = {(__bf16)aq[0][0], (__bf16)aq[0][1], (__bf16)aq[0][2], (__bf16)aq[0][3]};
    bf16x4 p1 = {(__bf16)aq[1][0], (__bf16)aq[1][1], (__bf16)aq[1][2], (__bf16)aq[1][3]};
    *(bf16x4*)&ldsQt[lr][w * 16 + lg * 4] = p0;
    *(bf16x4*)&ldsQt[16 + lr][w * 16 + lg * 4] = p1;
#pragma unroll
    for (int r = 0; r < 4; ++r) {
      ldsKtN[w * 16 + lg * 4 + r][lr] = (__bf16)ak[0][r];
      ldsKtN[w * 16 + lg * 4 + r][16 + lr] = (__bf16)ak[1][r];
    }
  }
  __syncthreads();
  {  // Kt store: one ds_read_b128 + one 16B global store per thread
    int nloc = t >> 2, j0 = (t & 3) * 8;
    bf16x8 pk = *(const bf16x8*)&ldsKtN[nloc][j0];
    *(bf16x8*)&Kt_t[((size_t)b * NN + nsub + nloc) * NK + j0] = pk;
  }
  // T(256x32) = X Qt : A = x rows from global (L1/L2-hot), B = ldsQt rows
  f32x4 accT[4][2] = {};
#pragma unroll
  for (int ks2 = 0; ks2 < 2; ++ks2) {
    bf16x8 bf0 = *(const bf16x8*)&ldsQt[lr][ks2 * 32 + lg * 8];
    bf16x8 bf1 = *(const bf16x8*)&ldsQt[16 + lr][ks2 * 32 + lg * 8];
#pragma unroll
    for (int mt = 0; mt < 4; ++mt) {
      int c = w * 64 + mt * 16 + lr;
      bf16x8 af = load_bf8(xb + (size_t)c * NN + nsub + ks2 * 32 + lg * 8);
      accT[mt][0] = __builtin_amdgcn_mfma_f32_16x16x32_bf16(af, bf0, accT[mt][0], 0, 0, 0);
      accT[mt][1] = __builtin_amdgcn_mfma_f32_16x16x32_bf16(af, bf1, accT[mt][1], 0, 0, 0);
    }
  }
  // qsum partial
  qs0 += __shfl_xor(qs0, 16); qs0 += __shfl_xor(qs0, 32);
  qs1 += __shfl_xor(qs1, 16); qs1 += __shfl_xor(qs1, 32);
  if (lane < 16) { ldsQs[w][lane] = qs0; ldsQs[w][16 + lane] = qs1; }
  __syncthreads();
  if (t < 32)
    qsum_part[(size_t)(chunk * NB + b) * NK + t] =
        ldsQs[0][t] + ldsQs[1][t] + ldsQs[2][t] + ldsQs[3][t];
  // Tpart[chunk][b][j][c] bf16
  __bf16* Tp = Tpart + (size_t)(chunk * NB + b) * NC * NK;
#pragma unroll
  for (int mt = 0; mt < 4; ++mt)
#pragma unroll
    for (int jf = 0; jf < 2; ++jf) {
      bf16x4 pk = {(__bf16)accT[mt][jf][0], (__bf16)accT[mt][jf][1],
                   (__bf16)accT[mt][jf][2], (__bf16)accT[mt][jf][3]};
      *(bf16x4*)&Tp[(jf * 16 + lr) * NC + w * 64 + mt * 16 + lg * 4] = pk;
    }
}

// ---------------- reduce: Tq[half] = sum of 32-chunk half (f32) ---------------
// grid = NB*8*2 (128 blocks).  [R14 exact]
__global__ __launch_bounds__(256) void k_reduce(
    const __bf16* __restrict__ Tpart, float* __restrict__ Tq) {
  int bid = blockIdx.x;
  int b = bid >> 4, r = bid & 15;
  int js = r >> 1, half = r & 1;
  int t = threadIdx.x;
  int jo = t >> 6, c0 = (t & 63) * 4;
  const size_t chstride = (size_t)NB * NK * NC;
  size_t idx = ((size_t)b * NK + js * 4 + jo) * NC + c0;
  const __bf16* src = Tpart + (size_t)(half * 32) * chstride + idx;
  float acc[4] = {};
#pragma unroll 8
  for (int ch = 0; ch < 32; ++ch) {
    bf16x4 v = *(const bf16x4*)&src[ch * chstride];
#pragma unroll
    for (int i = 0; i < 4; ++i) acc[i] += (float)v[i];
  }
  f32x4 o = {acc[0], acc[1], acc[2], acc[3]};
  *(f32x4*)&Tq[((size_t)(half * NB + b) * NK + js * 4 + jo) * NC + c0] = o;
}

// ---------------- pgemm: P-half = Wv T_half + bv qsum^T ; h-half = P bk -------
// grid = NB*2 (16 blocks), 256 threads.  [R14 exact]
__global__ __launch_bounds__(256) void k_pgemm(
    const float* __restrict__ Tq, const float* __restrict__ qsum_part,
    const float* __restrict__ Wv, const float* __restrict__ bv,
    const float* __restrict__ bk, __bf16* __restrict__ P,
    float* __restrict__ h2) {
  __shared__ __bf16 shTt[16][264];  // T^T half [j][c]
  __shared__ float shQsum[16];
  int bid = blockIdx.x;
  int b = bid >> 1, jg = bid & 1;
  int t = threadIdx.x;
  if (t < 16) {
    float s = 0.f;
#pragma unroll 8
    for (int ch = 0; ch < NCHUNK; ++ch)
      s += qsum_part[(size_t)(ch * NB + b) * NK + jg * 16 + t];
    shQsum[t] = s;
  }
  {  // combine the two f32 halves into LDS T half (16j x 256c)
    int j = t >> 4, c0 = (t & 15) * 16;
    const float* s0 = Tq + ((size_t)b * NK + jg * 16 + j) * NC + c0;
    const float* s1 = Tq + ((size_t)(NB + b) * NK + jg * 16 + j) * NC + c0;
    __bf16 outv[16];
#pragma unroll
    for (int q = 0; q < 4; ++q) {
      f32x4 a = *(const f32x4*)(s0 + q * 4);
      f32x4 bb = *(const f32x4*)(s1 + q * 4);
#pragma unroll
      for (int i = 0; i < 4; ++i) outv[q * 4 + i] = (__bf16)(a[i] + bb[i]);
    }
    *(bf16x8*)&shTt[j][c0] = *(bf16x8*)&outv[0];
    *(bf16x8*)&shTt[j][c0 + 8] = *(bf16x8*)&outv[8];
  }
  __syncthreads();
  int lane = t & 63, w = t >> 6, lr = lane & 15, lg = lane >> 4;
  float bkj = bk[jg * 16 + lr];
  f32x4 accP[4] = {};
#pragma unroll
  for (int ks = 0; ks < 8; ++ks) {
    bf16x8 b0 = *(const bf16x8*)&shTt[lr][ks * 32 + lg * 8];
#pragma unroll
    for (int mt = 0; mt < 4; ++mt) {
      int c = w * 64 + mt * 16 + lr;
      bf16x8 af = load_bf8(Wv + (size_t)c * NC + ks * 32 + lg * 8);
      accP[mt] = __builtin_amdgcn_mfma_f32_16x16x32_bf16(af, b0, accP[mt], 0, 0, 0);
    }
  }
  float qs = shQsum[lr];
#pragma unroll
  for (int mt = 0; mt < 4; ++mt) {
    float hacc[4];
#pragma unroll
    for (int r = 0; r < 4; ++r) {
      int c = w * 64 + mt * 16 + lg * 4 + r;
      float val = accP[mt][r] + bv[c] * qs;
      P[((size_t)b * NC + c) * NK + jg * 16 + lr] = (__bf16)val;
      hacc[r] = val * bkj;
    }
#pragma unroll
    for (int r = 0; r < 4; ++r) {
      float v = hacc[r];
      v += __shfl_xor(v, 1); v += __shfl_xor(v, 2);
      v += __shfl_xor(v, 4); v += __shfl_xor(v, 8);
      if (lr == 0)
        h2[((size_t)b * 2 + jg) * NC + w * 64 + mt * 16 + lg * 4 + r] = v;
    }
  }
}

// ---------------- back: out = gamma*(P Kt + h 1^T) + x -----------------------
// grid = NB*128 (1024 blocks, 4/CU), 256 threads: 32-n tiles.  [R14 exact]
__global__ __launch_bounds__(256) void k_back(
    const float* __restrict__ x, const __bf16* __restrict__ Kt_t,
    const __bf16* __restrict__ P, const float* __restrict__ h2,
    const float* __restrict__ gamma, float* __restrict__ out) {
  int bid = blockIdx.x;
  int b = bid >> 7, n0 = (bid & 127) * 32;
  int t = threadIdx.x;
  int lane = t & 63, w = t >> 6, lr = lane & 15, lg = lane >> 4;
  int wn = w & 1, fh = w >> 1;

  bf16x8 af = *(const bf16x8*)&Kt_t[((size_t)b * NN + n0 + wn * 16 + lr) * NK + lg * 8];
  const __bf16* Pb = P + (size_t)b * NC * NK;
  f32x4 acc[8];
#pragma unroll
  for (int f8 = 0; f8 < 8; ++f8) {
    int ft = fh * 8 + f8;
    bf16x8 bfr = *(const bf16x8*)&Pb[(size_t)(ft * 16 + lr) * NK + lg * 8];
    f32x4 z = {0.f, 0.f, 0.f, 0.f};
    acc[f8] = __builtin_amdgcn_mfma_f32_16x16x32_bf16(af, bfr, z, 0, 0, 0);
  }
  float g = gamma[0];
  const float* h0 = h2 + (size_t)b * 2 * NC;
#pragma unroll
  for (int f8 = 0; f8 < 8; ++f8) {
    int ft = fh * 8 + f8;
    int c = ft * 16 + lr;
    float hc = h0[c] + h0[NC + c];
    size_t idx = ((size_t)b * NC + c) * NN + n0 + wn * 16 + lg * 4;
    f32x4 xv = *(const f32x4*)&x[idx];
    f32x4 o;
#pragma unroll
    for (int r = 0; r < 4; ++r) o[r] = g * (acc[f8][r] + hc) + xv[r];
    *(f32x4*)&out[idx] = o;
  }
}

extern "C" void kernel_launch(void* const* d_in, const int* in_sizes, int n_in,
                              void* d_out, int out_size, void* d_ws, size_t ws_size,
                              hipStream_t stream) {
  (void)in_sizes; (void)n_in; (void)out_size; (void)ws_size;
  const float* x     = (const float*)d_in[0];
  const float* Wk    = (const float*)d_in[1];
  const float* bk    = (const float*)d_in[2];
  const float* Wq    = (const float*)d_in[3];
  const float* bq    = (const float*)d_in[4];
  const float* Wv    = (const float*)d_in[5];
  const float* bv    = (const float*)d_in[6];
  const float* gamma = (const float*)d_in[7];
  float* out = (float*)d_out;

  char* wsb = (char*)d_ws;
  const size_t tpB = (size_t)NCHUNK * NB * NC * NK * 2;  // 8 MB
  const size_t ktB = (size_t)NB * NN * NK * 2;           // 2 MB
  const size_t qsB = (size_t)NCHUNK * NB * NK * 4;       // 64 KB
  const size_t pB  = (size_t)NB * NC * NK * 2;           // 128 KB
  const size_t h2B = (size_t)NB * 2 * NC * 4;            // 16 KB
  const size_t tqB = (size_t)2 * NB * NK * NC * 4;       // 512 KB
  __bf16* Tpart = (__bf16*)wsb;
  __bf16* Kt_t  = (__bf16*)(wsb + tpB);
  float*  qsp   = (float*)(wsb + tpB + ktB);
  __bf16* P     = (__bf16*)(wsb + tpB + ktB + qsB);
  float*  h2    = (float*)(wsb + tpB + ktB + qsB + pB);
  float*  Tq    = (float*)(wsb + tpB + ktB + qsB + pB + h2B);
  __bf16* Wqb   = (__bf16*)(wsb + tpB + ktB + qsB + pB + h2B + tqB);  // 16 KB
  __bf16* Wkb   = Wqb + (size_t)NK * NC;                              // 16 KB

  k_wprep<<<16, 256, 0, stream>>>(Wq, Wk, Wqb, Wkb);
  k_front<<<NB * NCHUNK, 256, 0, stream>>>(x, Wqb, bq, Wkb, Tpart, Kt_t, qsp);
  k_reduce<<<NB * 8 * 2, 256, 0, stream>>>(Tpart, Tq);
  k_pgemm<<<NB * 2, 256, 0, stream>>>(Tq, qsp, Wv, bv, bk, P, h2);
  k_back<<<NB * 128, 256, 0, stream>>>(x, Kt_t, P, h2, gamma, out);
}

// Round 16
// 50.810 us; speedup vs baseline: 1.1908x; 1.1908x over previous
//
#include <hip/hip_runtime.h>

// SelfAttention2d, B=8 C=256 H=W=64 (N=4096), Ck=32, softmax dead code.
// out = gamma * (v q^T k) + x, reassociated:
//   Qt = X^T Wq^T + 1 bq^T      (N x 32, per-tile, LDS only)
//   Kt_t = X^T Wk^T             (N x 32, bf16, ws; bk folded into h)
//   T  = X Qt                   (256 x 32) n-chunked partials -> ws
//   qsum = Qt^T 1               (32)
//   P  = Wv T + bv qsum^T       (256 x 32), h = P bk  (j-split over 2 blocks)
//   out = gamma * (P Kt + h 1^T) + x
// R16 = R14 restored byte-identical (champion, 51.2 us). R15's ldsW removal
// regressed 9 us: global B-frags are lane-scattered across 16 W rows -> 16
// cache lines per wave load vs ~2-cycle LDS reads. ldsW stays.

constexpr int NB = 8;
constexpr int NC = 256;
constexpr int NK = 32;     // C/8
constexpr int NN = 4096;   // H*W
constexpr int NCHUNK = 64; // front n-chunks (64 n each)

typedef float  f32x4  __attribute__((ext_vector_type(4)));
typedef __bf16 bf16x4 __attribute__((ext_vector_type(4)));
typedef __bf16 bf16x8 __attribute__((ext_vector_type(8)));

__device__ __forceinline__ bf16x8 load_bf8(const float* __restrict__ p) {
  f32x4 a = *(const f32x4*)p;
  f32x4 b = *(const f32x4*)(p + 4);
  bf16x8 r;
  r[0] = (__bf16)a[0]; r[1] = (__bf16)a[1]; r[2] = (__bf16)a[2]; r[3] = (__bf16)a[3];
  r[4] = (__bf16)b[0]; r[5] = (__bf16)b[1]; r[6] = (__bf16)b[2]; r[7] = (__bf16)b[3];
  return r;
}

// ---------------- front: Qt/Kt for one 64-n subtile; T partial; qsum partial --
// grid = NB*64 (512 blocks, 2/CU), 256 threads (4 waves).
__global__ __launch_bounds__(256) void k_front(
    const float* __restrict__ x, const float* __restrict__ Wq,
    const float* __restrict__ bq, const float* __restrict__ Wk,
    __bf16* __restrict__ Tpart, __bf16* __restrict__ Kt_t,
    float* __restrict__ qsum_part) {
  __shared__ __bf16 ldsT[64 * 264];   // x-subtile transposed [n][c], XOR-swizzled
  __shared__ __bf16 ldsW[2][32][264]; // Wq, Wk bf16 [j][c]
  __shared__ __bf16 ldsQt[32][72];    // Q^T subtile [j][n]
  __shared__ __bf16 ldsKtN[64][40];   // K^T subtile [n][j] (80B rows, 16B-aligned)
  __shared__ float  ldsQs[4][32];
  int bid = blockIdx.x;
  int b = bid >> 6, chunk = bid & 63;
  int nsub = chunk * 64;
  int t = threadIdx.x;
  int lane = t & 63, w = t >> 6, lr = lane & 15, lg = lane >> 4;
  const float* xb = x + (size_t)b * NC * NN;
  float bq0 = bq[lr], bq1 = bq[16 + lr];

  {  // weight stage: Wq/Wk f32[32][256] -> ldsW bf16, once per block
    int m = t >> 7, tid = t & 127;
    int j = tid >> 2, c0 = (tid & 3) * 64;
    const float* Ws = m ? Wk : Wq;
#pragma unroll
    for (int i = 0; i < 16; ++i) {
      f32x4 v = *(const f32x4*)(Ws + j * NC + c0 + i * 4);
      bf16x4 pk = {(__bf16)v[0], (__bf16)v[1], (__bf16)v[2], (__bf16)v[3]};
      *(bf16x4*)&ldsW[m][j][c0 + i * 4] = pk;
    }
  }
  {  // stage x[0:256][nsub:nsub+64] -> ldsT swizzled, fully coalesced reads
    int cg = t >> 4, ng = t & 15;
    int n0 = ng * 4;
    int swzEl = (ng & 7) << 3;
#pragma unroll
    for (int r = 0; r < 4; ++r) {
      int c0 = r * 64 + cg * 4;
      const float* src = xb + (size_t)c0 * NN + nsub + n0;
      f32x4 L0 = *(const f32x4*)(src);
      f32x4 L1 = *(const f32x4*)(src + NN);
      f32x4 L2 = *(const f32x4*)(src + 2 * NN);
      f32x4 L3 = *(const f32x4*)(src + 3 * NN);
#pragma unroll
      for (int jj = 0; jj < 4; ++jj) {
        bf16x4 pk = {(__bf16)L0[jj], (__bf16)L1[jj], (__bf16)L2[jj], (__bf16)L3[jj]};
        *(bf16x4*)&ldsT[(n0 + jj) * 264 + (c0 ^ swzEl)] = pk;
      }
    }
  }
  __syncthreads();
  // Qt(64x32) and Kt(64x32): all-LDS operands; A-frag reads use the swizzle
  f32x4 aq[2] = {}, ak[2] = {};
  {
    int n = w * 16 + lr;
    int swzA = ((n >> 2) & 7) << 3;
    int rowA = n * 264;
#pragma unroll
    for (int ks = 0; ks < 8; ++ks) {
      bf16x8 af = *(const bf16x8*)&ldsT[rowA + ((ks * 32 + lg * 8) ^ swzA)];
      bf16x8 q0 = *(const bf16x8*)&ldsW[0][lr][ks * 32 + lg * 8];
      bf16x8 q1 = *(const bf16x8*)&ldsW[0][16 + lr][ks * 32 + lg * 8];
      bf16x8 k0 = *(const bf16x8*)&ldsW[1][lr][ks * 32 + lg * 8];
      bf16x8 k1 = *(const bf16x8*)&ldsW[1][16 + lr][ks * 32 + lg * 8];
      aq[0] = __builtin_amdgcn_mfma_f32_16x16x32_bf16(af, q0, aq[0], 0, 0, 0);
      aq[1] = __builtin_amdgcn_mfma_f32_16x16x32_bf16(af, q1, aq[1], 0, 0, 0);
      ak[0] = __builtin_amdgcn_mfma_f32_16x16x32_bf16(af, k0, ak[0], 0, 0, 0);
      ak[1] = __builtin_amdgcn_mfma_f32_16x16x32_bf16(af, k1, ak[1], 0, 0, 0);
    }
  }
  float qs0, qs1;
#pragma unroll
  for (int r = 0; r < 4; ++r) { aq[0][r] += bq0; aq[1][r] += bq1; }
  qs0 = aq[0][0] + aq[0][1] + aq[0][2] + aq[0][3];
  qs1 = aq[1][0] + aq[1][1] + aq[1][2] + aq[1][3];
  {  // Qt -> LDS [j][n]; Kt -> LDS [n][j]
    bf16x4 p0 = {(__bf16)aq[0][0], (__bf16)aq[0][1], (__bf16)aq[0][2], (__bf16)aq[0][3]};
    bf16x4 p1 = {(__bf16)aq[1][0], (__bf16)aq[1][1], (__bf16)aq[1][2], (__bf16)aq[1][3]};
    *(bf16x4*)&ldsQt[lr][w * 16 + lg * 4] = p0;
    *(bf16x4*)&ldsQt[16 + lr][w * 16 + lg * 4] = p1;
#pragma unroll
    for (int r = 0; r < 4; ++r) {
      ldsKtN[w * 16 + lg * 4 + r][lr] = (__bf16)ak[0][r];
      ldsKtN[w * 16 + lg * 4 + r][16 + lr] = (__bf16)ak[1][r];
    }
  }
  __syncthreads();
  {  // Kt store: one ds_read_b128 + one 16B global store per thread
    int nloc = t >> 2, j0 = (t & 3) * 8;
    bf16x8 pk = *(const bf16x8*)&ldsKtN[nloc][j0];
    *(bf16x8*)&Kt_t[((size_t)b * NN + nsub + nloc) * NK + j0] = pk;
  }
  // T(256x32) = X Qt : A = x rows from global (L1/L2-hot), B = ldsQt rows
  f32x4 accT[4][2] = {};
#pragma unroll
  for (int ks2 = 0; ks2 < 2; ++ks2) {
    bf16x8 bf0 = *(const bf16x8*)&ldsQt[lr][ks2 * 32 + lg * 8];
    bf16x8 bf1 = *(const bf16x8*)&ldsQt[16 + lr][ks2 * 32 + lg * 8];
#pragma unroll
    for (int mt = 0; mt < 4; ++mt) {
      int c = w * 64 + mt * 16 + lr;
      bf16x8 af = load_bf8(xb + (size_t)c * NN + nsub + ks2 * 32 + lg * 8);
      accT[mt][0] = __builtin_amdgcn_mfma_f32_16x16x32_bf16(af, bf0, accT[mt][0], 0, 0, 0);
      accT[mt][1] = __builtin_amdgcn_mfma_f32_16x16x32_bf16(af, bf1, accT[mt][1], 0, 0, 0);
    }
  }
  // qsum partial
  qs0 += __shfl_xor(qs0, 16); qs0 += __shfl_xor(qs0, 32);
  qs1 += __shfl_xor(qs1, 16); qs1 += __shfl_xor(qs1, 32);
  if (lane < 16) { ldsQs[w][lane] = qs0; ldsQs[w][16 + lane] = qs1; }
  __syncthreads();
  if (t < 32)
    qsum_part[(size_t)(chunk * NB + b) * NK + t] =
        ldsQs[0][t] + ldsQs[1][t] + ldsQs[2][t] + ldsQs[3][t];
  // Tpart[chunk][b][j][c] bf16
  __bf16* Tp = Tpart + (size_t)(chunk * NB + b) * NC * NK;
#pragma unroll
  for (int mt = 0; mt < 4; ++mt)
#pragma unroll
    for (int jf = 0; jf < 2; ++jf) {
      bf16x4 pk = {(__bf16)accT[mt][jf][0], (__bf16)accT[mt][jf][1],
                   (__bf16)accT[mt][jf][2], (__bf16)accT[mt][jf][3]};
      *(bf16x4*)&Tp[(jf * 16 + lr) * NC + w * 64 + mt * 16 + lg * 4] = pk;
    }
}

// ---------------- reduce: Tq[half] = sum of 32-chunk half (f32) ---------------
// grid = NB*8*2 (128 blocks): block = (b, js: 4-j slice, half: chunk half).
__global__ __launch_bounds__(256) void k_reduce(
    const __bf16* __restrict__ Tpart, float* __restrict__ Tq) {
  int bid = blockIdx.x;
  int b = bid >> 4, r = bid & 15;
  int js = r >> 1, half = r & 1;
  int t = threadIdx.x;
  int jo = t >> 6, c0 = (t & 63) * 4;
  const size_t chstride = (size_t)NB * NK * NC;
  size_t idx = ((size_t)b * NK + js * 4 + jo) * NC + c0;
  const __bf16* src = Tpart + (size_t)(half * 32) * chstride + idx;
  float acc[4] = {};
#pragma unroll 8
  for (int ch = 0; ch < 32; ++ch) {
    bf16x4 v = *(const bf16x4*)&src[ch * chstride];
#pragma unroll
    for (int i = 0; i < 4; ++i) acc[i] += (float)v[i];
  }
  f32x4 o = {acc[0], acc[1], acc[2], acc[3]};
  *(f32x4*)&Tq[((size_t)(half * NB + b) * NK + js * 4 + jo) * NC + c0] = o;
}

// ---------------- pgemm: P-half = Wv T_half + bv qsum^T ; h-half = P bk -------
// grid = NB*2 (16 blocks), 256 threads. Adds the two f32 Tq halves inline.
__global__ __launch_bounds__(256) void k_pgemm(
    const float* __restrict__ Tq, const float* __restrict__ qsum_part,
    const float* __restrict__ Wv, const float* __restrict__ bv,
    const float* __restrict__ bk, __bf16* __restrict__ P,
    float* __restrict__ h2) {
  __shared__ __bf16 shTt[16][264];  // T^T half [j][c]
  __shared__ float shQsum[16];
  int bid = blockIdx.x;
  int b = bid >> 1, jg = bid & 1;
  int t = threadIdx.x;
  if (t < 16) {
    float s = 0.f;
#pragma unroll 8
    for (int ch = 0; ch < NCHUNK; ++ch)
      s += qsum_part[(size_t)(ch * NB + b) * NK + jg * 16 + t];
    shQsum[t] = s;
  }
  {  // combine the two f32 halves into LDS T half (16j x 256c)
    int j = t >> 4, c0 = (t & 15) * 16;
    const float* s0 = Tq + ((size_t)b * NK + jg * 16 + j) * NC + c0;
    const float* s1 = Tq + ((size_t)(NB + b) * NK + jg * 16 + j) * NC + c0;
    __bf16 outv[16];
#pragma unroll
    for (int q = 0; q < 4; ++q) {
      f32x4 a = *(const f32x4*)(s0 + q * 4);
      f32x4 bb = *(const f32x4*)(s1 + q * 4);
#pragma unroll
      for (int i = 0; i < 4; ++i) outv[q * 4 + i] = (__bf16)(a[i] + bb[i]);
    }
    *(bf16x8*)&shTt[j][c0] = *(bf16x8*)&outv[0];
    *(bf16x8*)&shTt[j][c0 + 8] = *(bf16x8*)&outv[8];
  }
  __syncthreads();
  int lane = t & 63, w = t >> 6, lr = lane & 15, lg = lane >> 4;
  float bkj = bk[jg * 16 + lr];
  f32x4 accP[4] = {};
#pragma unroll
  for (int ks = 0; ks < 8; ++ks) {
    bf16x8 b0 = *(const bf16x8*)&shTt[lr][ks * 32 + lg * 8];
#pragma unroll
    for (int mt = 0; mt < 4; ++mt) {
      int c = w * 64 + mt * 16 + lr;
      bf16x8 af = load_bf8(Wv + (size_t)c * NC + ks * 32 + lg * 8);
      accP[mt] = __builtin_amdgcn_mfma_f32_16x16x32_bf16(af, b0, accP[mt], 0, 0, 0);
    }
  }
  float qs = shQsum[lr];
#pragma unroll
  for (int mt = 0; mt < 4; ++mt) {
    float hacc[4];
#pragma unroll
    for (int r = 0; r < 4; ++r) {
      int c = w * 64 + mt * 16 + lg * 4 + r;
      float val = accP[mt][r] + bv[c] * qs;
      P[((size_t)b * NC + c) * NK + jg * 16 + lr] = (__bf16)val;
      hacc[r] = val * bkj;
    }
#pragma unroll
    for (int r = 0; r < 4; ++r) {
      float v = hacc[r];
      v += __shfl_xor(v, 1); v += __shfl_xor(v, 2);
      v += __shfl_xor(v, 4); v += __shfl_xor(v, 8);
      if (lr == 0)
        h2[((size_t)b * 2 + jg) * NC + w * 64 + mt * 16 + lg * 4 + r] = v;
    }
  }
}

// ---------------- back: out = gamma*(P Kt + h 1^T) + x -----------------------
// grid = NB*128 (1024 blocks, 4/CU), 256 threads: 32-n tiles.
// Wave: n-half = w&1 (16 rows), ft-half = w>>1 (8 of 16 c-tiles). acc[8].
__global__ __launch_bounds__(256) void k_back(
    const float* __restrict__ x, const __bf16* __restrict__ Kt_t,
    const __bf16* __restrict__ P, const float* __restrict__ h2,
    const float* __restrict__ gamma, float* __restrict__ out) {
  int bid = blockIdx.x;
  int b = bid >> 7, n0 = (bid & 127) * 32;
  int t = threadIdx.x;
  int lane = t & 63, w = t >> 6, lr = lane & 15, lg = lane >> 4;
  int wn = w & 1, fh = w >> 1;

  bf16x8 af = *(const bf16x8*)&Kt_t[((size_t)b * NN + n0 + wn * 16 + lr) * NK + lg * 8];
  const __bf16* Pb = P + (size_t)b * NC * NK;
  f32x4 acc[8];
#pragma unroll
  for (int f8 = 0; f8 < 8; ++f8) {
    int ft = fh * 8 + f8;
    bf16x8 bfr = *(const bf16x8*)&Pb[(size_t)(ft * 16 + lr) * NK + lg * 8];
    f32x4 z = {0.f, 0.f, 0.f, 0.f};
    acc[f8] = __builtin_amdgcn_mfma_f32_16x16x32_bf16(af, bfr, z, 0, 0, 0);
  }
  float g = gamma[0];
  const float* h0 = h2 + (size_t)b * 2 * NC;
#pragma unroll
  for (int f8 = 0; f8 < 8; ++f8) {
    int ft = fh * 8 + f8;
    int c = ft * 16 + lr;
    float hc = h0[c] + h0[NC + c];
    size_t idx = ((size_t)b * NC + c) * NN + n0 + wn * 16 + lg * 4;
    f32x4 xv = *(const f32x4*)&x[idx];
    f32x4 o;
#pragma unroll
    for (int r = 0; r < 4; ++r) o[r] = g * (acc[f8][r] + hc) + xv[r];
    *(f32x4*)&out[idx] = o;
  }
}

extern "C" void kernel_launch(void* const* d_in, const int* in_sizes, int n_in,
                              void* d_out, int out_size, void* d_ws, size_t ws_size,
                              hipStream_t stream) {
  (void)in_sizes; (void)n_in; (void)out_size; (void)ws_size;
  const float* x     = (const float*)d_in[0];
  const float* Wk    = (const float*)d_in[1];
  const float* bk    = (const float*)d_in[2];
  const float* Wq    = (const float*)d_in[3];
  const float* bq    = (const float*)d_in[4];
  const float* Wv    = (const float*)d_in[5];
  const float* bv    = (const float*)d_in[6];
  const float* gamma = (const float*)d_in[7];
  float* out = (float*)d_out;

  char* wsb = (char*)d_ws;
  const size_t tpB = (size_t)NCHUNK * NB * NC * NK * 2;  // 8 MB
  const size_t ktB = (size_t)NB * NN * NK * 2;           // 2 MB
  const size_t qsB = (size_t)NCHUNK * NB * NK * 4;       // 64 KB
  const size_t pB  = (size_t)NB * NC * NK * 2;           // 128 KB
  const size_t h2B = (size_t)NB * 2 * NC * 4;            // 16 KB
  __bf16* Tpart = (__bf16*)wsb;
  __bf16* Kt_t  = (__bf16*)(wsb + tpB);
  float*  qsp   = (float*)(wsb + tpB + ktB);
  __bf16* P     = (__bf16*)(wsb + tpB + ktB + qsB);
  float*  h2    = (float*)(wsb + tpB + ktB + qsB + pB);
  float*  Tq    = (float*)(wsb + tpB + ktB + qsB + pB + h2B);  // 512 KB f32

  k_front<<<NB * NCHUNK, 256, 0, stream>>>(x, Wq, bq, Wk, Tpart, Kt_t, qsp);
  k_reduce<<<NB * 8 * 2, 256, 0, stream>>>(Tpart, Tq);
  k_pgemm<<<NB * 2, 256, 0, stream>>>(Tq, qsp, Wv, bv, bk, P, h2);
  k_back<<<NB * 128, 256, 0, stream>>>(x, Kt_t, P, h2, gamma, out);
}